// Round 1
// baseline (1818.157 us; speedup 1.0000x reference)
//
#include <hip/hip_runtime.h>

// Segment mean (sparse avg pool): sums via fp32 atomics into d_out,
// counts into d_ws, then divide in-place.
//
// Geometry: N_FINE=2,000,000 fine voxels, C=64 channels, N_COARSE=250,000.
// Thread mapping (scatter): 16 threads per fine voxel, each owns 4 channels
// via one float4 load (16 B/lane coalesced) + 4 global atomicAdds.

__global__ void __launch_bounds__(256)
seg_scatter_kernel(const float* __restrict__ feats,
                   const int* __restrict__ ids,
                   float* __restrict__ sums,
                   float* __restrict__ cnt,
                   int n_fine) {
    long long t = (long long)blockIdx.x * blockDim.x + threadIdx.x;
    int voxel = (int)(t >> 4);
    if (voxel >= n_fine) return;
    int c4 = ((int)t & 15) << 2;  // channel offset 0,4,...,60

    int seg = ids[voxel];
    const float4 v = *reinterpret_cast<const float4*>(feats + (long long)voxel * 64 + c4);

    float* dst = sums + (long long)seg * 64 + c4;
    atomicAdd(dst + 0, v.x);
    atomicAdd(dst + 1, v.y);
    atomicAdd(dst + 2, v.z);
    atomicAdd(dst + 3, v.w);

    if (((int)t & 15) == 0) atomicAdd(cnt + seg, 1.0f);
}

// out[i] (holding sums) *= (cnt[row] > 0 ? 1/cnt[row] : 0), float4-wide.
__global__ void __launch_bounds__(256)
seg_finalize_kernel(float* __restrict__ out,
                    const float* __restrict__ cnt,
                    int n4) {  // n4 = num_coarse * 16 float4's
    int i = blockIdx.x * blockDim.x + threadIdx.x;
    if (i >= n4) return;
    int row = i >> 4;  // 16 float4's per coarse row (64 ch)
    float c = cnt[row];
    float s = (c > 0.0f) ? (1.0f / c) : 0.0f;
    float4 v = reinterpret_cast<const float4*>(out)[i];
    v.x *= s; v.y *= s; v.z *= s; v.w *= s;
    reinterpret_cast<float4*>(out)[i] = v;
}

extern "C" void kernel_launch(void* const* d_in, const int* in_sizes, int n_in,
                              void* d_out, int out_size, void* d_ws, size_t ws_size,
                              hipStream_t stream) {
    const float* feats = (const float*)d_in[0];
    const int*   ids   = (const int*)d_in[1];
    // d_in[2] is the num_coarse scalar on DEVICE — can't read it on host under
    // graph capture; recover from out_size = num_coarse * 64.
    const int C = 64;
    const int num_coarse = out_size / C;
    const int n_fine = in_sizes[1];  // coarse_ids element count

    float* sums = (float*)d_out;     // accumulate directly into output
    float* cnt  = (float*)d_ws;      // num_coarse floats of scratch

    // Zero accumulators every call (d_out/d_ws are poisoned, not re-poisoned).
    hipMemsetAsync(sums, 0, (size_t)out_size * sizeof(float), stream);
    hipMemsetAsync(cnt,  0, (size_t)num_coarse * sizeof(float), stream);

    {
        long long threads = (long long)n_fine * 16;
        int blocks = (int)((threads + 255) / 256);
        seg_scatter_kernel<<<blocks, 256, 0, stream>>>(feats, ids, sums, cnt, n_fine);
    }
    {
        int n4 = out_size / 4;
        int blocks = (n4 + 255) / 256;
        seg_finalize_kernel<<<blocks, 256, 0, stream>>>(sums, cnt, n4);
    }
}

// Round 2
// 387.706 us; speedup vs baseline: 4.6895x; 4.6895x over previous
//
#include <hip/hip_runtime.h>

// Segment mean (sparse avg pool), gather formulation.
// N_FINE=2M fine voxels x C=64 ch fp32 -> N_COARSE=250K coarse voxels.
//
// Round-1 scatter version was L2-RMW bound (WRITE_SIZE 2.1 GB for 64 MB out).
// Here: build CSR (counts -> exclusive scan -> index fill), then one gather
// pass: 16 lanes per coarse voxel, one float4 column per lane. No float
// atomics; int atomics touch only ~1 MB (L2-resident).

#define SCAN_B 256
#define SCAN_E 1024  // elems per scan block (4/thread)

// ---- pass 1: histogram of coarse ids ----
__global__ void __launch_bounds__(256)
count_kernel(const int* __restrict__ ids, int* __restrict__ counts, int n) {
    int i4 = (blockIdx.x * 256 + threadIdx.x) * 4;
    if (i4 + 3 < n) {
        int4 v = *reinterpret_cast<const int4*>(ids + i4);
        atomicAdd(&counts[v.x], 1);
        atomicAdd(&counts[v.y], 1);
        atomicAdd(&counts[v.z], 1);
        atomicAdd(&counts[v.w], 1);
    } else {
        for (int i = i4; i < n; ++i) atomicAdd(&counts[ids[i]], 1);
    }
}

// ---- pass 2a: per-block exclusive scan; block sums to partials ----
__global__ void __launch_bounds__(SCAN_B)
scan1_kernel(const int* __restrict__ counts, int* __restrict__ off,
             int* __restrict__ partials, int n_total, int nc) {
    __shared__ int sh[SCAN_B];
    int tid = threadIdx.x;
    int base = blockIdx.x * SCAN_E + tid * 4;
    int c[4];
    #pragma unroll
    for (int k = 0; k < 4; ++k) {
        int idx = base + k;
        c[k] = (idx < nc) ? counts[idx] : 0;  // virtual 0 beyond nc (incl. idx==nc)
    }
    int tsum = c[0] + c[1] + c[2] + c[3];
    sh[tid] = tsum;
    __syncthreads();
    for (int d = 1; d < SCAN_B; d <<= 1) {
        int v = (tid >= d) ? sh[tid - d] : 0;
        __syncthreads();
        sh[tid] += v;
        __syncthreads();
    }
    int incl = sh[tid];
    if (tid == SCAN_B - 1) partials[blockIdx.x] = incl;
    int excl = incl - tsum;
    #pragma unroll
    for (int k = 0; k < 4; ++k) {
        int idx = base + k;
        if (idx < n_total) off[idx] = excl;
        excl += c[k];
    }
}

// ---- pass 2b: exclusive scan of block partials (single block, <=256) ----
__global__ void __launch_bounds__(SCAN_B)
scan2_kernel(int* __restrict__ partials, int nparts) {
    __shared__ int sh[SCAN_B];
    int tid = threadIdx.x;
    int own = (tid < nparts) ? partials[tid] : 0;
    sh[tid] = own;
    __syncthreads();
    for (int d = 1; d < SCAN_B; d <<= 1) {
        int v = (tid >= d) ? sh[tid - d] : 0;
        __syncthreads();
        sh[tid] += v;
        __syncthreads();
    }
    if (tid < nparts) partials[tid] = sh[tid] - own;  // exclusive
}

// ---- pass 2c: add block bases; init cursors ----
__global__ void __launch_bounds__(256)
scan3_kernel(int* __restrict__ off, const int* __restrict__ partials,
             int* __restrict__ cur, int n_total, int nc) {
    int i = blockIdx.x * 256 + threadIdx.x;
    if (i >= n_total) return;
    int v = off[i] + partials[i / SCAN_E];
    off[i] = v;
    if (i < nc) cur[i] = v;
}

// ---- pass 3: fill CSR index list ----
__global__ void __launch_bounds__(256)
fill_kernel(const int* __restrict__ ids, int* __restrict__ cur,
            int* __restrict__ idxs, int n) {
    int v = blockIdx.x * 256 + threadIdx.x;
    if (v >= n) return;
    int seg = ids[v];
    int pos = atomicAdd(&cur[seg], 1);
    idxs[pos] = v;
}

// ---- pass 4: gather + mean. 16 lanes/segment, one float4 column/lane ----
__global__ void __launch_bounds__(256)
gather_kernel(const float* __restrict__ feats, const int* __restrict__ off,
              const int* __restrict__ idxs, float* __restrict__ out,
              int num_coarse) {
    int t = blockIdx.x * 256 + threadIdx.x;
    int seg = t >> 4;
    if (seg >= num_coarse) return;
    int q = (t & 15) << 2;  // channel offset 0,4,...,60

    int s = off[seg], e = off[seg + 1];
    float4 acc = make_float4(0.f, 0.f, 0.f, 0.f);
    int j = s;
    for (; j + 1 < e; j += 2) {  // unroll x2 for two in-flight loads
        int v0 = idxs[j], v1 = idxs[j + 1];
        float4 a = *reinterpret_cast<const float4*>(feats + (long long)v0 * 64 + q);
        float4 b = *reinterpret_cast<const float4*>(feats + (long long)v1 * 64 + q);
        acc.x += a.x + b.x;
        acc.y += a.y + b.y;
        acc.z += a.z + b.z;
        acc.w += a.w + b.w;
    }
    if (j < e) {
        int v0 = idxs[j];
        float4 a = *reinterpret_cast<const float4*>(feats + (long long)v0 * 64 + q);
        acc.x += a.x; acc.y += a.y; acc.z += a.z; acc.w += a.w;
    }
    int cnt = e - s;
    float inv = (cnt > 0) ? (1.0f / (float)cnt) : 0.0f;
    acc.x *= inv; acc.y *= inv; acc.z *= inv; acc.w *= inv;
    *reinterpret_cast<float4*>(out + (long long)seg * 64 + q) = acc;
}

// ---- fallback (ws too small): round-1 atomic scatter ----
__global__ void __launch_bounds__(256)
seg_scatter_kernel(const float* __restrict__ feats, const int* __restrict__ ids,
                   float* __restrict__ sums, float* __restrict__ cnt, int n_fine) {
    long long t = (long long)blockIdx.x * blockDim.x + threadIdx.x;
    int voxel = (int)(t >> 4);
    if (voxel >= n_fine) return;
    int c4 = ((int)t & 15) << 2;
    int seg = ids[voxel];
    const float4 v = *reinterpret_cast<const float4*>(feats + (long long)voxel * 64 + c4);
    float* dst = sums + (long long)seg * 64 + c4;
    atomicAdd(dst + 0, v.x);
    atomicAdd(dst + 1, v.y);
    atomicAdd(dst + 2, v.z);
    atomicAdd(dst + 3, v.w);
    if (((int)t & 15) == 0) atomicAdd(cnt + seg, 1.0f);
}

__global__ void __launch_bounds__(256)
seg_finalize_kernel(float* __restrict__ out, const float* __restrict__ cnt, int n4) {
    int i = blockIdx.x * 256 + threadIdx.x;
    if (i >= n4) return;
    int row = i >> 4;
    float c = cnt[row];
    float s = (c > 0.0f) ? (1.0f / c) : 0.0f;
    float4 v = reinterpret_cast<const float4*>(out)[i];
    v.x *= s; v.y *= s; v.z *= s; v.w *= s;
    reinterpret_cast<float4*>(out)[i] = v;
}

extern "C" void kernel_launch(void* const* d_in, const int* in_sizes, int n_in,
                              void* d_out, int out_size, void* d_ws, size_t ws_size,
                              hipStream_t stream) {
    const float* feats = (const float*)d_in[0];
    const int*   ids   = (const int*)d_in[1];
    const int C = 64;
    const int nc = out_size / C;        // num_coarse (d_in[2] is device-only)
    const int n_fine = in_sizes[1];
    float* out = (float*)d_out;

    // workspace layout (ints)
    const int n_total = nc + 1;
    const int nparts = (n_total + SCAN_E - 1) / SCAN_E;
    size_t need = ((size_t)n_total + nc + n_fine + 256 + nc) * sizeof(int);

    if (ws_size < need || nparts > SCAN_B) {
        // fallback: atomic scatter (round-1 path)
        float* cnt = (float*)d_ws;
        hipMemsetAsync(out, 0, (size_t)out_size * sizeof(float), stream);
        hipMemsetAsync(cnt, 0, (size_t)nc * sizeof(float), stream);
        long long threads = (long long)n_fine * 16;
        seg_scatter_kernel<<<(int)((threads + 255) / 256), 256, 0, stream>>>(
            feats, ids, out, cnt, n_fine);
        int n4 = out_size / 4;
        seg_finalize_kernel<<<(n4 + 255) / 256, 256, 0, stream>>>(out, cnt, n4);
        return;
    }

    int* off      = (int*)d_ws;          // [nc+1] exclusive offsets
    int* cur      = off + n_total;       // [nc]   fill cursors
    int* idxs     = cur + nc;            // [n_fine] CSR voxel indices
    int* partials = idxs + n_fine;       // [256]  scan partials
    int* counts   = partials + 256;      // [nc]   histogram

    hipMemsetAsync(counts, 0, (size_t)nc * sizeof(int), stream);

    {   // histogram
        int nquads = (n_fine + 3) / 4;
        count_kernel<<<(nquads + 255) / 256, 256, 0, stream>>>(ids, counts, n_fine);
    }
    {   // exclusive scan counts -> off, init cur
        scan1_kernel<<<nparts, SCAN_B, 0, stream>>>(counts, off, partials, n_total, nc);
        scan2_kernel<<<1, SCAN_B, 0, stream>>>(partials, nparts);
        scan3_kernel<<<(n_total + 255) / 256, 256, 0, stream>>>(off, partials, cur, n_total, nc);
    }
    {   // CSR fill
        fill_kernel<<<(n_fine + 255) / 256, 256, 0, stream>>>(ids, cur, idxs, n_fine);
    }
    {   // gather + mean
        long long threads = (long long)nc * 16;
        gather_kernel<<<(int)((threads + 255) / 256), 256, 0, stream>>>(
            feats, off, idxs, out, nc);
    }
}